// Round 3
// baseline (18183.603 us; speedup 1.0000x reference)
//
#include <hip/hip_runtime.h>
#include <stdint.h>
#include <math.h>

typedef __attribute__((ext_vector_type(8))) short bf16x8;
typedef __attribute__((ext_vector_type(4))) float f32x4;
typedef __attribute__((ext_vector_type(4))) unsigned short us4;
typedef __attribute__((ext_vector_type(4))) unsigned int ui4;

// ---------------- workspace layout (bytes) ----------------
constexpr size_t OFF_FLAGS  = 0;                          // 256 * 4
constexpr size_t OFF_RING_H = 4096;                       // [2 ring][2 dir][64 b][512 k] bf16 = 262144
constexpr size_t OFF_RING_M = OFF_RING_H + 262144;
constexpr size_t OFF_RING_L = OFF_RING_M + 262144;
constexpr size_t OFF_MASK   = OFF_RING_L + 262144;        // [512 t][64 b] f32 = 131072
constexpr size_t OFF_XE_H   = OFF_MASK + 131072;          // [512 t][64 b][256 k] bf16 = 16777216
constexpr size_t OFF_XE_L   = OFF_XE_H + 16777216;
constexpr size_t OFF_HSEQ   = OFF_XE_L + 16777216;        // [2 dir][64 b][512 t][512 k] f32 = 134217728
constexpr size_t OFF_HLAST  = OFF_HSEQ + 134217728;       // [2 dir][64 b][512 k] f32 = 262144
constexpr size_t OFF_EMIS   = OFF_HLAST + 262144;         // [64 b][512 t][12] f32 = 1572864
// total ~170.5 MB

__device__ __forceinline__ unsigned short f2bf(float f) {
  unsigned u = __float_as_uint(f);
  unsigned r = 0x7fffu + ((u >> 16) & 1u);          // RNE
  return (unsigned short)((u + r) >> 16);
}
__device__ __forceinline__ float bf2f(unsigned short h) {
  return __uint_as_float(((unsigned)h) << 16);
}
__device__ __forceinline__ void split2(float v, unsigned short &a, unsigned short &b) {
  a = f2bf(v); b = f2bf(v - bf2f(a));
}
__device__ __forceinline__ void split3(float v, unsigned short &a, unsigned short &b, unsigned short &c) {
  a = f2bf(v); float r = v - bf2f(a);
  b = f2bf(r); float r2 = r - bf2f(b);
  c = f2bf(r2);
}
__device__ __forceinline__ float sigm(float x) {
  float e = expf(-fabsf(x));
  float s = 1.0f / (1.0f + e);
  return x >= 0.0f ? s : 1.0f - s;
}
__device__ __forceinline__ f32x4 mfma16(bf16x8 a, bf16x8 b, f32x4 c) {
  return __builtin_amdgcn_mfma_f32_16x16x32_bf16(a, b, c, 0, 0, 0);
}

// ---------------- prep: embeddings gather + hi/lo split, mask, zero-init ----------------
__global__ __launch_bounds__(256) void prep_k(const int* __restrict__ x,
                                              const float* __restrict__ emb,
                                              char* __restrict__ ws)
{
  const int bid = blockIdx.x, tid = threadIdx.x;
  if (bid < 8192) {                       // xe: 32768 rows x 64 segs (4 floats each)
    const int gi = bid * 256 + tid;
    const int row = gi >> 6;              // b*512 + t
    const int k = (gi & 63) * 4;
    const int b = row >> 9, t = row & 511;
    const int xid = x[row];
    const float4 v = *(const float4*)(emb + (size_t)xid * 256 + k);
    float vv[4] = {v.x, v.y, v.z, v.w};
    us4 H, L;
    #pragma unroll
    for (int j = 0; j < 4; ++j) {
      unsigned short hj, lj;
      split2(vv[j], hj, lj);
      H[j] = hj; L[j] = lj;
    }
    const size_t o = ((size_t)t * 64 + b) * 256 + k;
    *(us4*)((unsigned short*)(ws + OFF_XE_H) + o) = H;
    *(us4*)((unsigned short*)(ws + OFF_XE_L) + o) = L;
  } else if (bid < 8320) {                // mask
    const int gi = (bid - 8192) * 256 + tid;   // b*512 + t
    const int b = gi >> 9, t = gi & 511;
    ((float*)(ws + OFF_MASK))[t * 64 + b] = (x[gi] != 0) ? 1.0f : 0.0f;
  } else if (bid < 8512) {                // zero all three ring planes (contiguous 786432 B)
    const int gi = (bid - 8320) * 256 + tid;
    ui4 z = {0u, 0u, 0u, 0u};
    ((ui4*)(ws + OFF_RING_H))[gi] = z;
  } else {                                // zero barrier flags
    ((int*)(ws + OFF_FLAGS))[tid] = 0;
  }
}

// ---------------- persistent bidirectional LSTM (3-way-split bf16 MFMA, ~fp32-exact) ----------------
// 256 WGs x 256 threads. WG owns (dir, mhalf: 32 batch rows, nch: 8 h-cols -> 32 gate cols).
// Wave kh = tid>>6 (0..3) owns K tiles Kt = 4*kt+kh (h, kt=0..3) and Kt = 16+2*kh+xi (x, xi=0..1).
__global__ __launch_bounds__(256, 1) void lstm_k(
    const float* __restrict__ wih_f, const float* __restrict__ whh_f, const float* __restrict__ b_f,
    const float* __restrict__ wih_b, const float* __restrict__ whh_b, const float* __restrict__ b_b,
    char* __restrict__ ws)
{
  int* flags = (int*)(ws + OFF_FLAGS);
  unsigned short* ringH = (unsigned short*)(ws + OFF_RING_H);
  unsigned short* ringM = (unsigned short*)(ws + OFF_RING_M);
  unsigned short* ringL = (unsigned short*)(ws + OFF_RING_L);
  const float* maskf = (const float*)(ws + OFF_MASK);
  const unsigned short* xeH = (const unsigned short*)(ws + OFF_XE_H);
  const unsigned short* xeL = (const unsigned short*)(ws + OFF_XE_L);
  float* hseq  = (float*)(ws + OFF_HSEQ);
  float* hlast = (float*)(ws + OFF_HLAST);

  const int bid = blockIdx.x, tid = threadIdx.x;
  const int x8  = bid & 7;                 // fwd on XCD 0-3, bwd on 4-7
  const int dir = (x8 < 4) ? 0 : 1;
  const int idx = (bid >> 3) * 4 + (x8 & 3);   // 0..127 within direction
  const int mhalf = idx >> 6;              // 0..1
  const int nch   = idx & 63;              // 0..63  (8 h-cols each)

  const float* whh  = dir ? whh_b : whh_f;
  const float* wih  = dir ? wih_b : wih_f;
  const float* bias = dir ? b_b  : b_f;

  const int kh = tid >> 6, lane = tid & 63;
  const int quad = lane >> 4, n16 = lane & 15;

  // B-operand (W^T) fragments, 3-way split, in registers
  bf16x8 bhh[4][2][3];   // [kt][ni][plane]
  bf16x8 bhx[2][2][3];   // [xi][ni][plane]
  #pragma unroll
  for (int ni = 0; ni < 2; ++ni) {
    const int g = ni * 2 + (n16 >> 3);               // gate 0..3 (i,f,g,o)
    const int grow = g * 512 + nch * 8 + (n16 & 7);  // weight row (gate column)
    const float* hrow = whh + (size_t)grow * 512;
    const float* xrow = wih + (size_t)grow * 256;
    #pragma unroll
    for (int kt = 0; kt < 4; ++kt) {
      const int k = (4 * kt + kh) * 32 + quad * 8;
      union { bf16x8 v; unsigned short s[8]; } H, M, L;
      #pragma unroll
      for (int j = 0; j < 8; ++j) split3(hrow[k + j], H.s[j], M.s[j], L.s[j]);
      bhh[kt][ni][0] = H.v; bhh[kt][ni][1] = M.v; bhh[kt][ni][2] = L.v;
    }
    #pragma unroll
    for (int xi = 0; xi < 2; ++xi) {
      const int k = (2 * kh + xi) * 32 + quad * 8;
      union { bf16x8 v; unsigned short s[8]; } H, M, L;
      #pragma unroll
      for (int j = 0; j < 8; ++j) split3(xrow[k + j], H.s[j], M.s[j], L.s[j]);
      bhx[xi][ni][0] = H.v; bhx[xi][ni][1] = M.v; bhx[xi][ni][2] = L.v;
    }
  }

  // cell-update mapping: 256 threads = 32 rows x 8 h-cols
  const int rowU = tid & 31, jU = tid >> 5;
  const int bU = mhalf * 32 + rowU;
  const int hcol = nch * 8 + jU;
  const float bI = bias[hcol];
  const float bF = bias[512 + hcol];
  const float bG = bias[1024 + hcol];
  const float bO = bias[1536 + hcol];
  float cstate = 0.0f, hcarry = 0.0f;

  __shared__ float gbuf[4][32][33];   // [kh][row][col(+pad)]

  #pragma unroll 1
  for (int t = 0; t < 512; ++t) {
    const int tau = dir ? (511 - t) : t;
    f32x4 acc[2][2];
    const f32x4 z4 = {0.f, 0.f, 0.f, 0.f};
    #pragma unroll
    for (int mi = 0; mi < 2; ++mi)
      #pragma unroll
      for (int ni = 0; ni < 2; ++ni) acc[mi][ni] = z4;

    // ---- x-projection tiles: independent of other WGs, issued before the barrier ----
    #pragma unroll
    for (int xi = 0; xi < 2; ++xi) {
      const int kx = (2 * kh + xi) * 32 + quad * 8;
      #pragma unroll
      for (int mi = 0; mi < 2; ++mi) {
        const int row = mhalf * 32 + mi * 16 + n16;
        const size_t o = ((size_t)tau * 64 + row) * 256 + kx;
        bf16x8 aH = *(const bf16x8*)(xeH + o);
        bf16x8 aL = *(const bf16x8*)(xeL + o);
        #pragma unroll
        for (int ni = 0; ni < 2; ++ni) {
          f32x4 a = acc[mi][ni];
          a = mfma16(aH, bhx[xi][ni][0], a);
          a = mfma16(aH, bhx[xi][ni][1], a);
          a = mfma16(aL, bhx[xi][ni][0], a);
          a = mfma16(aL, bhx[xi][ni][1], a);
          acc[mi][ni] = a;
        }
      }
    }

    // ---- device-wide barrier: wait until every WG finished step t-1 ----
    if (tid < 64) {
      const int base = tid * 4;
      while (true) {
        int a0 = __hip_atomic_load(&flags[base + 0], __ATOMIC_RELAXED, __HIP_MEMORY_SCOPE_AGENT);
        int a1 = __hip_atomic_load(&flags[base + 1], __ATOMIC_RELAXED, __HIP_MEMORY_SCOPE_AGENT);
        int a2 = __hip_atomic_load(&flags[base + 2], __ATOMIC_RELAXED, __HIP_MEMORY_SCOPE_AGENT);
        int a3 = __hip_atomic_load(&flags[base + 3], __ATOMIC_RELAXED, __HIP_MEMORY_SCOPE_AGENT);
        if (a0 >= t && a1 >= t && a2 >= t && a3 >= t) break;
        __builtin_amdgcn_s_sleep(2);
      }
    }
    __threadfence();    // acquire
    __syncthreads();

    // ---- recurrent tiles reading h ring[p] (3-way split, 6 terms) ----
    const int p = t & 1;
    #pragma unroll
    for (int kt = 0; kt < 4; ++kt) {
      const int k = (4 * kt + kh) * 32 + quad * 8;
      #pragma unroll
      for (int mi = 0; mi < 2; ++mi) {
        const int row = mhalf * 32 + mi * 16 + n16;
        const size_t o = (((size_t)p * 2 + dir) * 64 + row) * 512 + k;
        bf16x8 aH = *(const bf16x8*)(ringH + o);
        bf16x8 aM = *(const bf16x8*)(ringM + o);
        bf16x8 aL = *(const bf16x8*)(ringL + o);
        #pragma unroll
        for (int ni = 0; ni < 2; ++ni) {
          f32x4 a = acc[mi][ni];
          a = mfma16(aH, bhh[kt][ni][0], a);
          a = mfma16(aH, bhh[kt][ni][1], a);
          a = mfma16(aM, bhh[kt][ni][0], a);
          a = mfma16(aH, bhh[kt][ni][2], a);
          a = mfma16(aM, bhh[kt][ni][1], a);
          a = mfma16(aL, bhh[kt][ni][0], a);
          acc[mi][ni] = a;
        }
      }
    }

    // ---- gates -> LDS (C/D layout: col = lane&15, row = quad*4 + reg) ----
    #pragma unroll
    for (int mi = 0; mi < 2; ++mi)
      #pragma unroll
      for (int ni = 0; ni < 2; ++ni)
        #pragma unroll
        for (int r = 0; r < 4; ++r)
          gbuf[kh][mi * 16 + quad * 4 + r][ni * 16 + n16] = acc[mi][ni][r];
    __syncthreads();

    // ---- LSTM cell update ----
    const float gi = gbuf[0][rowU][jU]      + gbuf[1][rowU][jU]      + gbuf[2][rowU][jU]      + gbuf[3][rowU][jU]      + bI;
    const float gf = gbuf[0][rowU][8 + jU]  + gbuf[1][rowU][8 + jU]  + gbuf[2][rowU][8 + jU]  + gbuf[3][rowU][8 + jU]  + bF;
    const float gg = gbuf[0][rowU][16 + jU] + gbuf[1][rowU][16 + jU] + gbuf[2][rowU][16 + jU] + gbuf[3][rowU][16 + jU] + bG;
    const float go = gbuf[0][rowU][24 + jU] + gbuf[1][rowU][24 + jU] + gbuf[2][rowU][24 + jU] + gbuf[3][rowU][24 + jU] + bO;
    const float m = maskf[tau * 64 + bU];
    const float iv = sigm(gi), fv = sigm(gf), gv = tanhf(gg), ov = sigm(go);
    const float cn = fv * cstate + iv * gv;
    const float hn = ov * tanhf(cn);
    const bool mm = (m > 0.5f);
    cstate = mm ? cn : cstate;
    hcarry = mm ? hn : hcarry;
    {
      unsigned short hb, mb, lb;
      split3(hcarry, hb, mb, lb);
      const size_t ri = (((size_t)(1 - p) * 2 + dir) * 64 + bU) * 512 + hcol;
      ringH[ri] = hb;
      ringM[ri] = mb;
      ringL[ri] = lb;
      hseq[(((size_t)dir * 64 + bU) * 512 + tau) * 512 + hcol] = mm ? hn : 0.0f;
    }
    __syncthreads();
    if (tid == 0) {
      __threadfence();  // release
      __hip_atomic_store(&flags[bid], t + 1, __ATOMIC_RELAXED, __HIP_MEMORY_SCOPE_AGENT);
    }
  }

  hlast[((size_t)dir * 64 + bU) * 512 + hcol] = hcarry;
}

// ---------------- emissions: hiddens @ fc_w^T + fc_b (fp64 accumulate) ----------------
__global__ __launch_bounds__(256) void emis_k(const float* __restrict__ fc_w,
                                              const float* __restrict__ fc_b,
                                              char* __restrict__ ws)
{
  __shared__ __align__(16) float fw[12 * 1024];
  __shared__ float fb[12];
  const int tid = threadIdx.x;
  for (int i = tid; i < 12 * 1024; i += 256) fw[i] = fc_w[i];
  if (tid < 12) fb[tid] = fc_b[tid];
  __syncthreads();
  const int row = blockIdx.x * 256 + tid;   // b*512 + tau
  const int b = row >> 9, tau = row & 511;
  const float* hs = (const float*)(ws + OFF_HSEQ);
  double acc[12];
  #pragma unroll
  for (int n = 0; n < 12; ++n) acc[n] = (double)fb[n];
  #pragma unroll 1
  for (int d = 0; d < 2; ++d) {
    const float4* hp = (const float4*)(hs + (((size_t)d * 64 + b) * 512 + tau) * 512);
    const float* fwd = fw + d * 512;
    for (int k4 = 0; k4 < 128; ++k4) {
      const float4 hv = hp[k4];
      #pragma unroll
      for (int n = 0; n < 12; ++n) {
        const float4 wv = *(const float4*)(fwd + n * 1024 + k4 * 4);
        acc[n] += (double)hv.x * wv.x + (double)hv.y * wv.y
                + (double)hv.z * wv.z + (double)hv.w * wv.w;
      }
    }
  }
  float* em = (float*)(ws + OFF_EMIS);
  #pragma unroll
  for (int n = 0; n < 12; ++n) em[(size_t)row * 12 + n] = (float)acc[n];
}

// ---------------- Viterbi decode (one wave per batch element) ----------------
__global__ __launch_bounds__(64) void viterbi_k(const float* __restrict__ trans,
                                                char* __restrict__ ws,
                                                float* __restrict__ out)
{
  const int b = blockIdx.x, lane = threadIdx.x;
  const float* eb = (const float*)(ws + OFF_EMIS) + (size_t)b * 6144;
  const float* maskf = (const float*)(ws + OFF_MASK);
  __shared__ float se[6144];
  __shared__ float sm[512];
  __shared__ unsigned char bp[512][12];
  for (int i = lane; i < 6144; i += 64) se[i] = eb[i];
  for (int i = lane; i < 512; i += 64) sm[i] = maskf[i * 64 + b];
  __syncthreads();
  const bool act = lane < 12;
  float tr[12];                         // tr[i] = trans[i][lane]
  #pragma unroll
  for (int i = 0; i < 12; ++i) tr[i] = act ? trans[i * 12 + lane] : 0.0f;
  float alpha = act ? (trans[120 + lane] + se[lane]) : -3.0e38f;   // BOS=10
  for (int t = 1; t < 512; ++t) {
    const float m = sm[t];
    float best = -3.0e38f; int bpi = 0;
    #pragma unroll
    for (int i = 0; i < 12; ++i) {
      const float s = __shfl(alpha, i) + tr[i];
      if (s > best) { best = s; bpi = i; }   // strict > keeps first max (jnp.argmax)
    }
    const float ev = act ? se[t * 12 + lane] : 0.0f;
    if (m > 0.5f) alpha = best + ev; else bpi = lane;
    if (act) bp[t][lane] = (unsigned char)bpi;
  }
  const float fin = act ? (alpha + trans[lane * 12 + 11]) : -3.0e38f;  // EOS=11
  float bestf = -3.0e38f; int bt = 0;
  #pragma unroll
  for (int j = 0; j < 12; ++j) {
    const float v = __shfl(fin, j);
    if (v > bestf) { bestf = v; bt = j; }
  }
  __syncthreads();
  if (lane == 0) {
    out[b] = bestf;
    int tag = bt;
    for (int t = 511; t >= 1; --t) {
      out[64 + (size_t)b * 512 + t] = (sm[t] > 0.5f) ? (float)tag : 0.0f;  // PAD=0
      tag = bp[t][tag];
    }
    out[64 + (size_t)b * 512] = (float)tag;   // t=0 always valid (len >= 256)
  }
}

// ---------------- classifier head: softmax(last_hidden @ fc2_w^T + fc2_b) ----------------
__global__ __launch_bounds__(64) void cls_k(const float* __restrict__ fc2_w,
                                            const float* __restrict__ fc2_b,
                                            char* __restrict__ ws,
                                            float* __restrict__ out)
{
  const int b = blockIdx.x, lane = threadIdx.x;
  const float* hl = (const float*)(ws + OFF_HLAST);
  float acc[10];
  #pragma unroll
  for (int c = 0; c < 10; ++c) acc[c] = 0.0f;
  #pragma unroll 1
  for (int kk = 0; kk < 16; ++kk) {
    const int k = lane * 16 + kk;
    const float hv = (k < 512) ? hl[(size_t)b * 512 + k]
                               : hl[((size_t)(64 + b)) * 512 + (k - 512)];
    #pragma unroll
    for (int c = 0; c < 10; ++c) acc[c] += hv * fc2_w[c * 1024 + k];
  }
  #pragma unroll
  for (int c = 0; c < 10; ++c) {
    #pragma unroll
    for (int off = 32; off >= 1; off >>= 1)
      acc[c] += __shfl_down(acc[c], off);
  }
  if (lane == 0) {
    float lg[10];
    float mx = -3.0e38f;
    #pragma unroll
    for (int c = 0; c < 10; ++c) { lg[c] = acc[c] + fc2_b[c]; mx = fmaxf(mx, lg[c]); }
    float s = 0.0f;
    #pragma unroll
    for (int c = 0; c < 10; ++c) { lg[c] = expf(lg[c] - mx); s += lg[c]; }
    const float inv = 1.0f / s;
    #pragma unroll
    for (int c = 0; c < 10; ++c) out[32832 + b * 10 + c] = lg[c] * inv;
  }
}

extern "C" void kernel_launch(void* const* d_in, const int* in_sizes, int n_in,
                              void* d_out, int out_size, void* d_ws, size_t ws_size,
                              hipStream_t stream)
{
  (void)in_sizes; (void)n_in; (void)out_size; (void)ws_size;
  const int*   x      = (const int*)d_in[0];
  const float* emb    = (const float*)d_in[1];
  const float* wih_f  = (const float*)d_in[2];
  const float* whh_f  = (const float*)d_in[3];
  const float* b_f    = (const float*)d_in[4];
  const float* wih_b  = (const float*)d_in[5];
  const float* whh_b  = (const float*)d_in[6];
  const float* b_b    = (const float*)d_in[7];
  const float* fc_w   = (const float*)d_in[8];
  const float* fc_b   = (const float*)d_in[9];
  const float* fc2_w  = (const float*)d_in[10];
  const float* fc2_b  = (const float*)d_in[11];
  const float* trans  = (const float*)d_in[12];
  char* ws = (char*)d_ws;
  float* out = (float*)d_out;

  prep_k<<<dim3(8513), dim3(256), 0, stream>>>(x, emb, ws);
  lstm_k<<<dim3(256), dim3(256), 0, stream>>>(wih_f, whh_f, b_f, wih_b, whh_b, b_b, ws);
  emis_k<<<dim3(128), dim3(256), 0, stream>>>(fc_w, fc_b, ws);
  cls_k<<<dim3(64), dim3(64), 0, stream>>>(fc2_w, fc2_b, ws, out);
  viterbi_k<<<dim3(64), dim3(64), 0, stream>>>(trans, ws, out);
}

// Round 4
// 4966.333 us; speedup vs baseline: 3.6614x; 3.6614x over previous
//
#include <hip/hip_runtime.h>
#include <stdint.h>
#include <math.h>

typedef __attribute__((ext_vector_type(8))) short bf16x8;
typedef __attribute__((ext_vector_type(4))) float f32x4;
typedef __attribute__((ext_vector_type(4))) unsigned short us4;
typedef __attribute__((ext_vector_type(4))) unsigned int ui4;

// ---------------- workspace layout (bytes) ----------------
constexpr size_t OFF_FLAGS  = 0;                          // 256 * 4
constexpr size_t OFF_RING_H = 4096;                       // [2 ring][2 dir][64 b][512 k] bf16 = 262144
constexpr size_t OFF_RING_M = OFF_RING_H + 262144;
constexpr size_t OFF_RING_L = OFF_RING_M + 262144;
constexpr size_t OFF_MASK   = OFF_RING_L + 262144;        // [512 t][64 b] f32 = 131072
constexpr size_t OFF_XE_H   = OFF_MASK + 131072;          // [512 t][64 b][256 k] bf16 = 16777216
constexpr size_t OFF_XE_L   = OFF_XE_H + 16777216;
constexpr size_t OFF_HSEQ   = OFF_XE_L + 16777216;        // [2 dir][64 b][512 t][512 k] f32 = 134217728
constexpr size_t OFF_HLAST  = OFF_HSEQ + 134217728;       // [2 dir][64 b][512 k] f32 = 262144
constexpr size_t OFF_EMIS   = OFF_HLAST + 262144;         // [64 b][512 t][12] f32 = 1572864
// total ~170.5 MB

__device__ __forceinline__ unsigned short f2bf(float f) {
  unsigned u = __float_as_uint(f);
  unsigned r = 0x7fffu + ((u >> 16) & 1u);          // RNE
  return (unsigned short)((u + r) >> 16);
}
__device__ __forceinline__ float bf2f(unsigned short h) {
  return __uint_as_float(((unsigned)h) << 16);
}
__device__ __forceinline__ void split2(float v, unsigned short &a, unsigned short &b) {
  a = f2bf(v); b = f2bf(v - bf2f(a));
}
__device__ __forceinline__ void split3(float v, unsigned short &a, unsigned short &b, unsigned short &c) {
  a = f2bf(v); float r = v - bf2f(a);
  b = f2bf(r); float r2 = r - bf2f(b);
  c = f2bf(r2);
}
__device__ __forceinline__ float sigm(float x) {
  float e = expf(-fabsf(x));
  float s = 1.0f / (1.0f + e);
  return x >= 0.0f ? s : 1.0f - s;
}
__device__ __forceinline__ f32x4 mfma16(bf16x8 a, bf16x8 b, f32x4 c) {
  return __builtin_amdgcn_mfma_f32_16x16x32_bf16(a, b, c, 0, 0, 0);
}
// L3-coherent (agent-scope, fence-free) ring I/O
__device__ __forceinline__ unsigned long long ald64(const unsigned short* p) {
  return __hip_atomic_load((const unsigned long long*)p, __ATOMIC_RELAXED, __HIP_MEMORY_SCOPE_AGENT);
}
__device__ __forceinline__ void ast32(unsigned int* p, unsigned v) {
  __hip_atomic_store(p, v, __ATOMIC_RELAXED, __HIP_MEMORY_SCOPE_AGENT);
}
__device__ __forceinline__ bf16x8 ring_frag(const unsigned short* base, size_t o) {
  union { bf16x8 v; unsigned long long q[2]; } u;
  u.q[0] = ald64(base + o);
  u.q[1] = ald64(base + o + 4);
  return u.v;
}

// ---------------- prep: embeddings gather + hi/lo split, mask, zero-init ----------------
__global__ __launch_bounds__(256) void prep_k(const int* __restrict__ x,
                                              const float* __restrict__ emb,
                                              char* __restrict__ ws)
{
  const int bid = blockIdx.x, tid = threadIdx.x;
  if (bid < 8192) {                       // xe: 32768 rows x 64 segs (4 floats each)
    const int gi = bid * 256 + tid;
    const int row = gi >> 6;              // b*512 + t
    const int k = (gi & 63) * 4;
    const int b = row >> 9, t = row & 511;
    const int xid = x[row];
    const float4 v = *(const float4*)(emb + (size_t)xid * 256 + k);
    float vv[4] = {v.x, v.y, v.z, v.w};
    us4 H, L;
    #pragma unroll
    for (int j = 0; j < 4; ++j) {
      unsigned short hj, lj;
      split2(vv[j], hj, lj);
      H[j] = hj; L[j] = lj;
    }
    const size_t o = ((size_t)t * 64 + b) * 256 + k;
    *(us4*)((unsigned short*)(ws + OFF_XE_H) + o) = H;
    *(us4*)((unsigned short*)(ws + OFF_XE_L) + o) = L;
  } else if (bid < 8320) {                // mask
    const int gi = (bid - 8192) * 256 + tid;   // b*512 + t
    const int b = gi >> 9, t = gi & 511;
    ((float*)(ws + OFF_MASK))[t * 64 + b] = (x[gi] != 0) ? 1.0f : 0.0f;
  } else if (bid < 8512) {                // zero all three ring planes (contiguous 786432 B)
    const int gi = (bid - 8320) * 256 + tid;
    ui4 z = {0u, 0u, 0u, 0u};
    ((ui4*)(ws + OFF_RING_H))[gi] = z;
  } else {                                // zero barrier flags
    ((int*)(ws + OFF_FLAGS))[tid] = 0;
  }
}

// ---------------- persistent bidirectional LSTM (3-way-split bf16 MFMA, ~fp32-exact) ----------------
// 256 WGs x 256 threads. WG owns (dir, mhalf: 32 batch rows, nch: 8 h-cols -> 32 gate cols).
// Wave kh = tid>>6 (0..3) owns K tiles Kt = 4*kt+kh (h, kt=0..3) and Kt = 16+2*kh+xi (x, xi=0..1).
// NO fences in the loop: ring data moves via agent-scope (L3 coherence point) atomics only.
__global__ __launch_bounds__(256, 1) void lstm_k(
    const float* __restrict__ wih_f, const float* __restrict__ whh_f, const float* __restrict__ b_f,
    const float* __restrict__ wih_b, const float* __restrict__ whh_b, const float* __restrict__ b_b,
    char* __restrict__ ws)
{
  int* flags = (int*)(ws + OFF_FLAGS);
  unsigned short* ringH = (unsigned short*)(ws + OFF_RING_H);
  unsigned short* ringM = (unsigned short*)(ws + OFF_RING_M);
  unsigned short* ringL = (unsigned short*)(ws + OFF_RING_L);
  const float* maskf = (const float*)(ws + OFF_MASK);
  const unsigned short* xeH = (const unsigned short*)(ws + OFF_XE_H);
  const unsigned short* xeL = (const unsigned short*)(ws + OFF_XE_L);
  float* hseq  = (float*)(ws + OFF_HSEQ);
  float* hlast = (float*)(ws + OFF_HLAST);

  const int bid = blockIdx.x, tid = threadIdx.x;
  const int x8  = bid & 7;                 // fwd on XCD 0-3, bwd on 4-7
  const int dir = (x8 < 4) ? 0 : 1;
  const int idx = (bid >> 3) * 4 + (x8 & 3);   // 0..127 within direction
  const int mhalf = idx >> 6;              // 0..1
  const int nch   = idx & 63;              // 0..63  (8 h-cols each)

  const float* whh  = dir ? whh_b : whh_f;
  const float* wih  = dir ? wih_b : wih_f;
  const float* bias = dir ? b_b  : b_f;

  const int kh = tid >> 6, lane = tid & 63;
  const int quad = lane >> 4, n16 = lane & 15;

  // B-operand (W^T) fragments, 3-way split, in registers
  bf16x8 bhh[4][2][3];   // [kt][ni][plane]
  bf16x8 bhx[2][2][3];   // [xi][ni][plane]
  #pragma unroll
  for (int ni = 0; ni < 2; ++ni) {
    const int g = ni * 2 + (n16 >> 3);               // gate 0..3 (i,f,g,o)
    const int grow = g * 512 + nch * 8 + (n16 & 7);  // weight row (gate column)
    const float* hrow = whh + (size_t)grow * 512;
    const float* xrow = wih + (size_t)grow * 256;
    #pragma unroll
    for (int kt = 0; kt < 4; ++kt) {
      const int k = (4 * kt + kh) * 32 + quad * 8;
      union { bf16x8 v; unsigned short s[8]; } H, M, L;
      #pragma unroll
      for (int j = 0; j < 8; ++j) split3(hrow[k + j], H.s[j], M.s[j], L.s[j]);
      bhh[kt][ni][0] = H.v; bhh[kt][ni][1] = M.v; bhh[kt][ni][2] = L.v;
    }
    #pragma unroll
    for (int xi = 0; xi < 2; ++xi) {
      const int k = (2 * kh + xi) * 32 + quad * 8;
      union { bf16x8 v; unsigned short s[8]; } H, M, L;
      #pragma unroll
      for (int j = 0; j < 8; ++j) split3(xrow[k + j], H.s[j], M.s[j], L.s[j]);
      bhx[xi][ni][0] = H.v; bhx[xi][ni][1] = M.v; bhx[xi][ni][2] = L.v;
    }
  }

  // cell-update mapping: 256 threads = 32 rows x 8 h-cols
  const int rowU = tid & 31, jU = tid >> 5;
  const int bU = mhalf * 32 + rowU;
  const int hcol = nch * 8 + jU;
  const float bI = bias[hcol];
  const float bF = bias[512 + hcol];
  const float bG = bias[1024 + hcol];
  const float bO = bias[1536 + hcol];
  float cstate = 0.0f, hcarry = 0.0f;

  __shared__ float gbuf[4][32][33];   // [kh][row][col(+pad)]

  #pragma unroll 1
  for (int t = 0; t < 512; ++t) {
    const int tau = dir ? (511 - t) : t;
    f32x4 acc[2][2];
    const f32x4 z4 = {0.f, 0.f, 0.f, 0.f};
    #pragma unroll
    for (int mi = 0; mi < 2; ++mi)
      #pragma unroll
      for (int ni = 0; ni < 2; ++ni) acc[mi][ni] = z4;

    // ---- x-projection tiles: independent of other WGs, issued before the barrier ----
    #pragma unroll
    for (int xi = 0; xi < 2; ++xi) {
      const int kx = (2 * kh + xi) * 32 + quad * 8;
      #pragma unroll
      for (int mi = 0; mi < 2; ++mi) {
        const int row = mhalf * 32 + mi * 16 + n16;
        const size_t o = ((size_t)tau * 64 + row) * 256 + kx;
        bf16x8 aH = *(const bf16x8*)(xeH + o);
        bf16x8 aL = *(const bf16x8*)(xeL + o);
        #pragma unroll
        for (int ni = 0; ni < 2; ++ni) {
          f32x4 a = acc[mi][ni];
          a = mfma16(aH, bhx[xi][ni][0], a);
          a = mfma16(aH, bhx[xi][ni][1], a);
          a = mfma16(aL, bhx[xi][ni][0], a);
          a = mfma16(aL, bhx[xi][ni][1], a);
          acc[mi][ni] = a;
        }
      }
    }

    // ---- device-wide barrier: wait until every WG finished step t-1 (no fence) ----
    if (tid < 64) {
      const int base = tid * 4;
      while (true) {
        int a0 = __hip_atomic_load(&flags[base + 0], __ATOMIC_RELAXED, __HIP_MEMORY_SCOPE_AGENT);
        int a1 = __hip_atomic_load(&flags[base + 1], __ATOMIC_RELAXED, __HIP_MEMORY_SCOPE_AGENT);
        int a2 = __hip_atomic_load(&flags[base + 2], __ATOMIC_RELAXED, __HIP_MEMORY_SCOPE_AGENT);
        int a3 = __hip_atomic_load(&flags[base + 3], __ATOMIC_RELAXED, __HIP_MEMORY_SCOPE_AGENT);
        if (a0 >= t && a1 >= t && a2 >= t && a3 >= t) break;
        __builtin_amdgcn_s_sleep(2);
      }
    }
    __syncthreads();

    // ---- recurrent tiles reading h ring[p] via L3 (agent-scope loads) ----
    const int p = t & 1;
    #pragma unroll
    for (int kt = 0; kt < 4; ++kt) {
      const int k = (4 * kt + kh) * 32 + quad * 8;
      #pragma unroll
      for (int mi = 0; mi < 2; ++mi) {
        const int row = mhalf * 32 + mi * 16 + n16;
        const size_t o = (((size_t)p * 2 + dir) * 64 + row) * 512 + k;
        bf16x8 aH = ring_frag(ringH, o);
        bf16x8 aM = ring_frag(ringM, o);
        bf16x8 aL = ring_frag(ringL, o);
        #pragma unroll
        for (int ni = 0; ni < 2; ++ni) {
          f32x4 a = acc[mi][ni];
          a = mfma16(aH, bhh[kt][ni][0], a);
          a = mfma16(aH, bhh[kt][ni][1], a);
          a = mfma16(aM, bhh[kt][ni][0], a);
          a = mfma16(aH, bhh[kt][ni][2], a);
          a = mfma16(aM, bhh[kt][ni][1], a);
          a = mfma16(aL, bhh[kt][ni][0], a);
          acc[mi][ni] = a;
        }
      }
    }

    // ---- gates -> LDS (C/D layout: col = lane&15, row = quad*4 + reg) ----
    #pragma unroll
    for (int mi = 0; mi < 2; ++mi)
      #pragma unroll
      for (int ni = 0; ni < 2; ++ni)
        #pragma unroll
        for (int r = 0; r < 4; ++r)
          gbuf[kh][mi * 16 + quad * 4 + r][ni * 16 + n16] = acc[mi][ni][r];
    __syncthreads();

    // ---- LSTM cell update ----
    const float gi = gbuf[0][rowU][jU]      + gbuf[1][rowU][jU]      + gbuf[2][rowU][jU]      + gbuf[3][rowU][jU]      + bI;
    const float gf = gbuf[0][rowU][8 + jU]  + gbuf[1][rowU][8 + jU]  + gbuf[2][rowU][8 + jU]  + gbuf[3][rowU][8 + jU]  + bF;
    const float gg = gbuf[0][rowU][16 + jU] + gbuf[1][rowU][16 + jU] + gbuf[2][rowU][16 + jU] + gbuf[3][rowU][16 + jU] + bG;
    const float go = gbuf[0][rowU][24 + jU] + gbuf[1][rowU][24 + jU] + gbuf[2][rowU][24 + jU] + gbuf[3][rowU][24 + jU] + bO;
    const float m = maskf[tau * 64 + bU];
    const float iv = sigm(gi), fv = sigm(gf), gv = tanhf(gg), ov = sigm(go);
    const float cn = fv * cstate + iv * gv;
    const float hn = ov * tanhf(cn);
    const bool mm = (m > 0.5f);
    cstate = mm ? cn : cstate;
    hcarry = mm ? hn : hcarry;
    {
      unsigned short hb, mb, lb;
      split3(hcarry, hb, mb, lb);
      // pack adjacent h-columns (jU even/odd = lane ^ 32 within the wave) into 32-bit words
      const int hbo = __shfl_xor((int)hb, 32);
      const int mbo = __shfl_xor((int)mb, 32);
      const int lbo = __shfl_xor((int)lb, 32);
      const size_t ri = (((size_t)(1 - p) * 2 + dir) * 64 + bU) * 512 + hcol;
      if (lane < 32) {                    // even hcol lanes write the packed word
        const size_t ui = ri >> 1;
        ast32((unsigned int*)ringH + ui, (unsigned)(unsigned short)hb | ((unsigned)(unsigned short)hbo << 16));
        ast32((unsigned int*)ringM + ui, (unsigned)(unsigned short)mb | ((unsigned)(unsigned short)mbo << 16));
        ast32((unsigned int*)ringL + ui, (unsigned)(unsigned short)lb | ((unsigned)(unsigned short)lbo << 16));
      }
      hseq[(((size_t)dir * 64 + bU) * 512 + tau) * 512 + hcol] = mm ? hn : 0.0f;
    }
    __syncthreads();   // drains vmcnt(0): write-through ring stores are in L3 before the flag store
    if (tid == 0) {
      __hip_atomic_store(&flags[bid], t + 1, __ATOMIC_RELAXED, __HIP_MEMORY_SCOPE_AGENT);
    }
  }

  hlast[((size_t)dir * 64 + bU) * 512 + hcol] = hcarry;
}

// ---------------- emissions: hiddens @ fc_w^T + fc_b (fp64 accumulate) ----------------
__global__ __launch_bounds__(256) void emis_k(const float* __restrict__ fc_w,
                                              const float* __restrict__ fc_b,
                                              char* __restrict__ ws)
{
  __shared__ __align__(16) float fw[12 * 1024];
  __shared__ float fb[12];
  const int tid = threadIdx.x;
  for (int i = tid; i < 12 * 1024; i += 256) fw[i] = fc_w[i];
  if (tid < 12) fb[tid] = fc_b[tid];
  __syncthreads();
  const int row = blockIdx.x * 256 + tid;   // b*512 + tau
  const int b = row >> 9, tau = row & 511;
  const float* hs = (const float*)(ws + OFF_HSEQ);
  double acc[12];
  #pragma unroll
  for (int n = 0; n < 12; ++n) acc[n] = (double)fb[n];
  #pragma unroll 1
  for (int d = 0; d < 2; ++d) {
    const float4* hp = (const float4*)(hs + (((size_t)d * 64 + b) * 512 + tau) * 512);
    const float* fwd = fw + d * 512;
    for (int k4 = 0; k4 < 128; ++k4) {
      const float4 hv = hp[k4];
      #pragma unroll
      for (int n = 0; n < 12; ++n) {
        const float4 wv = *(const float4*)(fwd + n * 1024 + k4 * 4);
        acc[n] += (double)hv.x * wv.x + (double)hv.y * wv.y
                + (double)hv.z * wv.z + (double)hv.w * wv.w;
      }
    }
  }
  float* em = (float*)(ws + OFF_EMIS);
  #pragma unroll
  for (int n = 0; n < 12; ++n) em[(size_t)row * 12 + n] = (float)acc[n];
}

// ---------------- Viterbi decode (one wave per batch element) ----------------
__global__ __launch_bounds__(64) void viterbi_k(const float* __restrict__ trans,
                                                char* __restrict__ ws,
                                                float* __restrict__ out)
{
  const int b = blockIdx.x, lane = threadIdx.x;
  const float* eb = (const float*)(ws + OFF_EMIS) + (size_t)b * 6144;
  const float* maskf = (const float*)(ws + OFF_MASK);
  __shared__ float se[6144];
  __shared__ float sm[512];
  __shared__ unsigned char bp[512][12];
  for (int i = lane; i < 6144; i += 64) se[i] = eb[i];
  for (int i = lane; i < 512; i += 64) sm[i] = maskf[i * 64 + b];
  __syncthreads();
  const bool act = lane < 12;
  float tr[12];                         // tr[i] = trans[i][lane]
  #pragma unroll
  for (int i = 0; i < 12; ++i) tr[i] = act ? trans[i * 12 + lane] : 0.0f;
  float alpha = act ? (trans[120 + lane] + se[lane]) : -3.0e38f;   // BOS=10
  for (int t = 1; t < 512; ++t) {
    const float m = sm[t];
    float best = -3.0e38f; int bpi = 0;
    #pragma unroll
    for (int i = 0; i < 12; ++i) {
      const float s = __shfl(alpha, i) + tr[i];
      if (s > best) { best = s; bpi = i; }   // strict > keeps first max (jnp.argmax)
    }
    const float ev = act ? se[t * 12 + lane] : 0.0f;
    if (m > 0.5f) alpha = best + ev; else bpi = lane;
    if (act) bp[t][lane] = (unsigned char)bpi;
  }
  const float fin = act ? (alpha + trans[lane * 12 + 11]) : -3.0e38f;  // EOS=11
  float bestf = -3.0e38f; int bt = 0;
  #pragma unroll
  for (int j = 0; j < 12; ++j) {
    const float v = __shfl(fin, j);
    if (v > bestf) { bestf = v; bt = j; }
  }
  __syncthreads();
  if (lane == 0) {
    out[b] = bestf;
    int tag = bt;
    for (int t = 511; t >= 1; --t) {
      out[64 + (size_t)b * 512 + t] = (sm[t] > 0.5f) ? (float)tag : 0.0f;  // PAD=0
      tag = bp[t][tag];
    }
    out[64 + (size_t)b * 512] = (float)tag;   // t=0 always valid (len >= 256)
  }
}

// ---------------- classifier head: softmax(last_hidden @ fc2_w^T + fc2_b) ----------------
__global__ __launch_bounds__(64) void cls_k(const float* __restrict__ fc2_w,
                                            const float* __restrict__ fc2_b,
                                            char* __restrict__ ws,
                                            float* __restrict__ out)
{
  const int b = blockIdx.x, lane = threadIdx.x;
  const float* hl = (const float*)(ws + OFF_HLAST);
  float acc[10];
  #pragma unroll
  for (int c = 0; c < 10; ++c) acc[c] = 0.0f;
  #pragma unroll 1
  for (int kk = 0; kk < 16; ++kk) {
    const int k = lane * 16 + kk;
    const float hv = (k < 512) ? hl[(size_t)b * 512 + k]
                               : hl[((size_t)(64 + b)) * 512 + (k - 512)];
    #pragma unroll
    for (int c = 0; c < 10; ++c) acc[c] += hv * fc2_w[c * 1024 + k];
  }
  #pragma unroll
  for (int c = 0; c < 10; ++c) {
    #pragma unroll
    for (int off = 32; off >= 1; off >>= 1)
      acc[c] += __shfl_down(acc[c], off);
  }
  if (lane == 0) {
    float lg[10];
    float mx = -3.0e38f;
    #pragma unroll
    for (int c = 0; c < 10; ++c) { lg[c] = acc[c] + fc2_b[c]; mx = fmaxf(mx, lg[c]); }
    float s = 0.0f;
    #pragma unroll
    for (int c = 0; c < 10; ++c) { lg[c] = expf(lg[c] - mx); s += lg[c]; }
    const float inv = 1.0f / s;
    #pragma unroll
    for (int c = 0; c < 10; ++c) out[32832 + b * 10 + c] = lg[c] * inv;
  }
}

extern "C" void kernel_launch(void* const* d_in, const int* in_sizes, int n_in,
                              void* d_out, int out_size, void* d_ws, size_t ws_size,
                              hipStream_t stream)
{
  (void)in_sizes; (void)n_in; (void)out_size; (void)ws_size;
  const int*   x      = (const int*)d_in[0];
  const float* emb    = (const float*)d_in[1];
  const float* wih_f  = (const float*)d_in[2];
  const float* whh_f  = (const float*)d_in[3];
  const float* b_f    = (const float*)d_in[4];
  const float* wih_b  = (const float*)d_in[5];
  const float* whh_b  = (const float*)d_in[6];
  const float* b_b    = (const float*)d_in[7];
  const float* fc_w   = (const float*)d_in[8];
  const float* fc_b   = (const float*)d_in[9];
  const float* fc2_w  = (const float*)d_in[10];
  const float* fc2_b  = (const float*)d_in[11];
  const float* trans  = (const float*)d_in[12];
  char* ws = (char*)d_ws;
  float* out = (float*)d_out;

  prep_k<<<dim3(8513), dim3(256), 0, stream>>>(x, emb, ws);
  lstm_k<<<dim3(256), dim3(256), 0, stream>>>(wih_f, whh_f, b_f, wih_b, whh_b, b_b, ws);
  emis_k<<<dim3(128), dim3(256), 0, stream>>>(fc_w, fc_b, ws);
  cls_k<<<dim3(64), dim3(64), 0, stream>>>(fc2_w, fc2_b, ws, out);
  viterbi_k<<<dim3(64), dim3(64), 0, stream>>>(trans, ws, out);
}

// Round 5
// 2817.245 us; speedup vs baseline: 6.4544x; 1.7628x over previous
//
#include <hip/hip_runtime.h>
#include <stdint.h>
#include <math.h>

typedef __attribute__((ext_vector_type(8))) short bf16x8;
typedef __attribute__((ext_vector_type(4))) float f32x4;
typedef __attribute__((ext_vector_type(4))) unsigned short us4;
typedef __attribute__((ext_vector_type(4))) unsigned int ui4;

// ---------------- workspace layout (bytes) ----------------
constexpr size_t OFF_FLAGS  = 0;                          // 256 * 4
constexpr size_t OFF_RING_H = 4096;                       // [2 ring][2 dir][64 b][512 k] bf16 = 262144
constexpr size_t OFF_RING_M = OFF_RING_H + 262144;
constexpr size_t OFF_RING_L = OFF_RING_M + 262144;
constexpr size_t OFF_MASK   = OFF_RING_L + 262144;        // [512 t][64 b] f32 = 131072
constexpr size_t OFF_XE_H   = OFF_MASK + 131072;          // [512 t][64 b][256 k] bf16 = 16777216
constexpr size_t OFF_XE_L   = OFF_XE_H + 16777216;
constexpr size_t OFF_HSEQ   = OFF_XE_L + 16777216;        // [2 dir][64 b][512 t][512 k] f32 = 134217728
constexpr size_t OFF_HLAST  = OFF_HSEQ + 134217728;       // [2 dir][64 b][512 k] f32 = 262144
constexpr size_t OFF_EMIS   = OFF_HLAST + 262144;         // [64 b][512 t][12] f32 = 1572864
// total ~170.5 MB

__device__ __forceinline__ unsigned short f2bf(float f) {
  unsigned u = __float_as_uint(f);
  unsigned r = 0x7fffu + ((u >> 16) & 1u);          // RNE
  return (unsigned short)((u + r) >> 16);
}
__device__ __forceinline__ float bf2f(unsigned short h) {
  return __uint_as_float(((unsigned)h) << 16);
}
__device__ __forceinline__ void split2(float v, unsigned short &a, unsigned short &b) {
  a = f2bf(v); b = f2bf(v - bf2f(a));
}
__device__ __forceinline__ void split3(float v, unsigned short &a, unsigned short &b, unsigned short &c) {
  a = f2bf(v); float r = v - bf2f(a);
  b = f2bf(r); float r2 = r - bf2f(b);
  c = f2bf(r2);
}
__device__ __forceinline__ float sigm(float x) {
  float e = expf(-fabsf(x));
  float s = 1.0f / (1.0f + e);
  return x >= 0.0f ? s : 1.0f - s;
}
__device__ __forceinline__ f32x4 mfma16(bf16x8 a, bf16x8 b, f32x4 c) {
  return __builtin_amdgcn_mfma_f32_16x16x32_bf16(a, b, c, 0, 0, 0);
}
// L3-coherent (agent-scope, fence-free) ring I/O
__device__ __forceinline__ unsigned long long ald64(const unsigned short* p) {
  return __hip_atomic_load((const unsigned long long*)p, __ATOMIC_RELAXED, __HIP_MEMORY_SCOPE_AGENT);
}
__device__ __forceinline__ void ast32(unsigned int* p, unsigned v) {
  __hip_atomic_store(p, v, __ATOMIC_RELAXED, __HIP_MEMORY_SCOPE_AGENT);
}
__device__ __forceinline__ bf16x8 ring_frag(const unsigned short* base, size_t o) {
  union { bf16x8 v; unsigned long long q[2]; } u;
  u.q[0] = ald64(base + o);
  u.q[1] = ald64(base + o + 4);
  return u.v;
}

// ---------------- prep: embeddings gather + hi/lo split, mask, zero-init ----------------
__global__ __launch_bounds__(256) void prep_k(const int* __restrict__ x,
                                              const float* __restrict__ emb,
                                              char* __restrict__ ws)
{
  const int bid = blockIdx.x, tid = threadIdx.x;
  if (bid < 8192) {                       // xe: 32768 rows x 64 segs (4 floats each)
    const int gi = bid * 256 + tid;
    const int row = gi >> 6;              // b*512 + t
    const int k = (gi & 63) * 4;
    const int b = row >> 9, t = row & 511;
    const int xid = x[row];
    const float4 v = *(const float4*)(emb + (size_t)xid * 256 + k);
    float vv[4] = {v.x, v.y, v.z, v.w};
    us4 H, L;
    #pragma unroll
    for (int j = 0; j < 4; ++j) {
      unsigned short hj, lj;
      split2(vv[j], hj, lj);
      H[j] = hj; L[j] = lj;
    }
    const size_t o = ((size_t)t * 64 + b) * 256 + k;
    *(us4*)((unsigned short*)(ws + OFF_XE_H) + o) = H;
    *(us4*)((unsigned short*)(ws + OFF_XE_L) + o) = L;
  } else if (bid < 8320) {                // mask
    const int gi = (bid - 8192) * 256 + tid;   // b*512 + t
    const int b = gi >> 9, t = gi & 511;
    ((float*)(ws + OFF_MASK))[t * 64 + b] = (x[gi] != 0) ? 1.0f : 0.0f;
  } else if (bid < 8512) {                // zero all three ring planes (contiguous 786432 B)
    const int gi = (bid - 8320) * 256 + tid;
    ui4 z = {0u, 0u, 0u, 0u};
    ((ui4*)(ws + OFF_RING_H))[gi] = z;
  } else {                                // zero barrier flags
    ((int*)(ws + OFF_FLAGS))[tid] = 0;
  }
}

// ---------------- persistent bidirectional LSTM (3-way-split bf16 MFMA, ~fp32-exact) ----------------
// 256 WGs x 256 threads. WG = (dir, mg: 16 batch rows, ng: 16 h-cols -> 64 gate cols).
// (dir,mg) defines an INDEPENDENT group of 32 WGs: h for those rows is produced/consumed
// entirely within the group -> 32-flag group barrier, no cross-group coupling.
// Wave kh = tid>>6 (0..3) owns K tiles Kt = 4*kt+kh (h) and x tiles (2*kh+xi).
__global__ __launch_bounds__(256, 1) void lstm_k(
    const float* __restrict__ wih_f, const float* __restrict__ whh_f, const float* __restrict__ b_f,
    const float* __restrict__ wih_b, const float* __restrict__ whh_b, const float* __restrict__ b_b,
    char* __restrict__ ws)
{
  int* flags = (int*)(ws + OFF_FLAGS);
  unsigned short* ringH = (unsigned short*)(ws + OFF_RING_H);
  unsigned short* ringM = (unsigned short*)(ws + OFF_RING_M);
  unsigned short* ringL = (unsigned short*)(ws + OFF_RING_L);
  const float* maskf = (const float*)(ws + OFF_MASK);
  const unsigned short* xeH = (const unsigned short*)(ws + OFF_XE_H);
  const unsigned short* xeL = (const unsigned short*)(ws + OFF_XE_L);
  float* hseq  = (float*)(ws + OFF_HSEQ);
  float* hlast = (float*)(ws + OFF_HLAST);

  const int bid = blockIdx.x, tid = threadIdx.x;
  const int dir = bid & 1;
  const int mg  = (bid >> 1) & 3;          // batch group: rows [mg*16, mg*16+16)
  const int ng  = bid >> 3;                // 0..31: h-cols [ng*16, ng*16+16)
  int* gflags = flags + (dir * 4 + mg) * 32;   // group barrier: 32 flags (2 cache lines)

  const float* whh  = dir ? whh_b : whh_f;
  const float* wih  = dir ? wih_b : wih_f;
  const float* bias = dir ? b_b  : b_f;

  const int kh = tid >> 6, lane = tid & 63;
  const int quad = lane >> 4, n16 = lane & 15;
  const int bRow = mg * 16 + n16;          // A-operand row (batch index)

  // B-operand (W^T) fragments in registers: gate g = ni (0..3 = i,f,g,o)
  bf16x8 bhh[4][4][3];   // [kt][ni][plane] 3-way split
  bf16x8 bhx[2][4][2];   // [xi][ni][plane] 2-way split
  #pragma unroll
  for (int ni = 0; ni < 4; ++ni) {
    const int grow = ni * 512 + ng * 16 + n16;   // weight row (gate column)
    const float* hrow = whh + (size_t)grow * 512;
    const float* xrow = wih + (size_t)grow * 256;
    #pragma unroll
    for (int kt = 0; kt < 4; ++kt) {
      const int k = (4 * kt + kh) * 32 + quad * 8;
      union { bf16x8 v; unsigned short s[8]; } H, M, L;
      #pragma unroll
      for (int j = 0; j < 8; ++j) split3(hrow[k + j], H.s[j], M.s[j], L.s[j]);
      bhh[kt][ni][0] = H.v; bhh[kt][ni][1] = M.v; bhh[kt][ni][2] = L.v;
    }
    #pragma unroll
    for (int xi = 0; xi < 2; ++xi) {
      const int k = (2 * kh + xi) * 32 + quad * 8;
      union { bf16x8 v; unsigned short s[8]; } H, L;
      #pragma unroll
      for (int j = 0; j < 8; ++j) split2(xrow[k + j], H.s[j], L.s[j]);
      bhx[xi][ni][0] = H.v; bhx[xi][ni][1] = L.v;
    }
  }

  // cell-update mapping: 256 threads = 16 rows x 16 h-cols (hcU fastest -> coalesced)
  const int rowU = tid >> 4, hcU = tid & 15;
  const int bU = mg * 16 + rowU;
  const int hcol = ng * 16 + hcU;
  const float bI = bias[hcol];
  const float bF = bias[512 + hcol];
  const float bG = bias[1024 + hcol];
  const float bO = bias[1536 + hcol];
  float cstate = 0.0f, hcarry = 0.0f;

  __shared__ float gbuf[4][16][65];   // [kh][row][gatecol(+pad)]

  #pragma unroll 1
  for (int t = 0; t < 512; ++t) {
    const int tau = dir ? (511 - t) : t;
    f32x4 acc[4];
    const f32x4 z4 = {0.f, 0.f, 0.f, 0.f};
    #pragma unroll
    for (int ni = 0; ni < 4; ++ni) acc[ni] = z4;

    // ---- x-projection tiles: group-independent, issued before the barrier ----
    #pragma unroll
    for (int xi = 0; xi < 2; ++xi) {
      const int kx = (2 * kh + xi) * 32 + quad * 8;
      const size_t o = ((size_t)tau * 64 + bRow) * 256 + kx;
      bf16x8 aH = *(const bf16x8*)(xeH + o);
      bf16x8 aL = *(const bf16x8*)(xeL + o);
      #pragma unroll
      for (int ni = 0; ni < 4; ++ni) {
        f32x4 a = acc[ni];
        a = mfma16(aH, bhx[xi][ni][0], a);
        a = mfma16(aH, bhx[xi][ni][1], a);
        a = mfma16(aL, bhx[xi][ni][0], a);
        a = mfma16(aL, bhx[xi][ni][1], a);
        acc[ni] = a;
      }
    }

    // ---- group barrier: wait until the 32 group peers finished step t-1 ----
    if (tid < 32) {
      while (__hip_atomic_load(&gflags[tid], __ATOMIC_RELAXED, __HIP_MEMORY_SCOPE_AGENT) < t)
        __builtin_amdgcn_s_sleep(1);
    }
    __syncthreads();

    // ---- prefetch all recurrent frags (ring slot p), then MFMA ----
    const int p = t & 1;
    bf16x8 rf[4][3];
    {
      const size_t rb = (((size_t)p * 2 + dir) * 64 + bRow) * 512;
      #pragma unroll
      for (int kt = 0; kt < 4; ++kt) {
        const size_t o = rb + (4 * kt + kh) * 32 + quad * 8;
        rf[kt][0] = ring_frag(ringH, o);
        rf[kt][1] = ring_frag(ringM, o);
        rf[kt][2] = ring_frag(ringL, o);
      }
    }
    #pragma unroll
    for (int kt = 0; kt < 4; ++kt) {
      #pragma unroll
      for (int ni = 0; ni < 4; ++ni) {
        f32x4 a = acc[ni];
        a = mfma16(rf[kt][0], bhh[kt][ni][0], a);
        a = mfma16(rf[kt][0], bhh[kt][ni][1], a);
        a = mfma16(rf[kt][1], bhh[kt][ni][0], a);
        a = mfma16(rf[kt][0], bhh[kt][ni][2], a);
        a = mfma16(rf[kt][1], bhh[kt][ni][1], a);
        a = mfma16(rf[kt][2], bhh[kt][ni][0], a);
        acc[ni] = a;
      }
    }

    // ---- gates -> LDS (C/D layout: col = lane&15, row = quad*4 + reg) ----
    #pragma unroll
    for (int ni = 0; ni < 4; ++ni)
      #pragma unroll
      for (int r = 0; r < 4; ++r)
        gbuf[kh][quad * 4 + r][ni * 16 + n16] = acc[ni][r];
    __syncthreads();

    // ---- LSTM cell update ----
    const float gi = gbuf[0][rowU][hcU]      + gbuf[1][rowU][hcU]      + gbuf[2][rowU][hcU]      + gbuf[3][rowU][hcU]      + bI;
    const float gf = gbuf[0][rowU][16 + hcU] + gbuf[1][rowU][16 + hcU] + gbuf[2][rowU][16 + hcU] + gbuf[3][rowU][16 + hcU] + bF;
    const float gg = gbuf[0][rowU][32 + hcU] + gbuf[1][rowU][32 + hcU] + gbuf[2][rowU][32 + hcU] + gbuf[3][rowU][32 + hcU] + bG;
    const float go = gbuf[0][rowU][48 + hcU] + gbuf[1][rowU][48 + hcU] + gbuf[2][rowU][48 + hcU] + gbuf[3][rowU][48 + hcU] + bO;
    const float m = maskf[tau * 64 + bU];
    const float iv = sigm(gi), fv = sigm(gf), gv = tanhf(gg), ov = sigm(go);
    const float cn = fv * cstate + iv * gv;
    const float hn = ov * tanhf(cn);
    const bool mm = (m > 0.5f);
    cstate = mm ? cn : cstate;
    hcarry = mm ? hn : hcarry;

    hseq[(((size_t)dir * 64 + bU) * 512 + tau) * 512 + hcol] = mm ? hn : 0.0f;
    {
      unsigned short hb, mb, lb;
      split3(hcarry, hb, mb, lb);
      // pack adjacent h-cols (hcU even/odd = lane ^ 1) into 32-bit words
      const int hbo = __shfl_xor((int)hb, 1);
      const int mbo = __shfl_xor((int)mb, 1);
      const int lbo = __shfl_xor((int)lb, 1);
      if ((tid & 1) == 0) {
        const size_t ri = (((size_t)(1 - p) * 2 + dir) * 64 + bU) * 512 + hcol;
        const size_t ui = ri >> 1;
        ast32((unsigned int*)ringH + ui, (unsigned)(unsigned short)hb | ((unsigned)(unsigned short)hbo << 16));
        ast32((unsigned int*)ringM + ui, (unsigned)(unsigned short)mb | ((unsigned)(unsigned short)mbo << 16));
        ast32((unsigned int*)ringL + ui, (unsigned)(unsigned short)lb | ((unsigned)(unsigned short)lbo << 16));
      }
    }
    __syncthreads();   // drains vmcnt(0): ring stores are at the coherence point before the flag store
    if (tid == 0) {
      __hip_atomic_store(&gflags[ng], t + 1, __ATOMIC_RELAXED, __HIP_MEMORY_SCOPE_AGENT);
    }
  }

  hlast[((size_t)dir * 64 + bU) * 512 + hcol] = hcarry;
}

// ---------------- emissions: hiddens @ fc_w^T + fc_b (fp64 accumulate) ----------------
__global__ __launch_bounds__(256) void emis_k(const float* __restrict__ fc_w,
                                              const float* __restrict__ fc_b,
                                              char* __restrict__ ws)
{
  __shared__ __align__(16) float fw[12 * 1024];
  __shared__ float fb[12];
  const int tid = threadIdx.x;
  for (int i = tid; i < 12 * 1024; i += 256) fw[i] = fc_w[i];
  if (tid < 12) fb[tid] = fc_b[tid];
  __syncthreads();
  const int row = blockIdx.x * 256 + tid;   // b*512 + tau
  const int b = row >> 9, tau = row & 511;
  const float* hs = (const float*)(ws + OFF_HSEQ);
  double acc[12];
  #pragma unroll
  for (int n = 0; n < 12; ++n) acc[n] = (double)fb[n];
  #pragma unroll 1
  for (int d = 0; d < 2; ++d) {
    const float4* hp = (const float4*)(hs + (((size_t)d * 64 + b) * 512 + tau) * 512);
    const float* fwd = fw + d * 512;
    for (int k4 = 0; k4 < 128; ++k4) {
      const float4 hv = hp[k4];
      #pragma unroll
      for (int n = 0; n < 12; ++n) {
        const float4 wv = *(const float4*)(fwd + n * 1024 + k4 * 4);
        acc[n] += (double)hv.x * wv.x + (double)hv.y * wv.y
                + (double)hv.z * wv.z + (double)hv.w * wv.w;
      }
    }
  }
  float* em = (float*)(ws + OFF_EMIS);
  #pragma unroll
  for (int n = 0; n < 12; ++n) em[(size_t)row * 12 + n] = (float)acc[n];
}

// ---------------- Viterbi decode (one wave per batch element) ----------------
__global__ __launch_bounds__(64) void viterbi_k(const float* __restrict__ trans,
                                                char* __restrict__ ws,
                                                float* __restrict__ out)
{
  const int b = blockIdx.x, lane = threadIdx.x;
  const float* eb = (const float*)(ws + OFF_EMIS) + (size_t)b * 6144;
  const float* maskf = (const float*)(ws + OFF_MASK);
  __shared__ float se[6144];
  __shared__ float sm[512];
  __shared__ unsigned char bp[512][12];
  for (int i = lane; i < 6144; i += 64) se[i] = eb[i];
  for (int i = lane; i < 512; i += 64) sm[i] = maskf[i * 64 + b];
  __syncthreads();
  const bool act = lane < 12;
  float tr[12];                         // tr[i] = trans[i][lane]
  #pragma unroll
  for (int i = 0; i < 12; ++i) tr[i] = act ? trans[i * 12 + lane] : 0.0f;
  float alpha = act ? (trans[120 + lane] + se[lane]) : -3.0e38f;   // BOS=10
  for (int t = 1; t < 512; ++t) {
    const float m = sm[t];
    float best = -3.0e38f; int bpi = 0;
    #pragma unroll
    for (int i = 0; i < 12; ++i) {
      const float s = __shfl(alpha, i) + tr[i];
      if (s > best) { best = s; bpi = i; }   // strict > keeps first max (jnp.argmax)
    }
    const float ev = act ? se[t * 12 + lane] : 0.0f;
    if (m > 0.5f) alpha = best + ev; else bpi = lane;
    if (act) bp[t][lane] = (unsigned char)bpi;
  }
  const float fin = act ? (alpha + trans[lane * 12 + 11]) : -3.0e38f;  // EOS=11
  float bestf = -3.0e38f; int bt = 0;
  #pragma unroll
  for (int j = 0; j < 12; ++j) {
    const float v = __shfl(fin, j);
    if (v > bestf) { bestf = v; bt = j; }
  }
  __syncthreads();
  if (lane == 0) {
    out[b] = bestf;
    int tag = bt;
    for (int t = 511; t >= 1; --t) {
      out[64 + (size_t)b * 512 + t] = (sm[t] > 0.5f) ? (float)tag : 0.0f;  // PAD=0
      tag = bp[t][tag];
    }
    out[64 + (size_t)b * 512] = (float)tag;   // t=0 always valid (len >= 256)
  }
}

// ---------------- classifier head: softmax(last_hidden @ fc2_w^T + fc2_b) ----------------
__global__ __launch_bounds__(64) void cls_k(const float* __restrict__ fc2_w,
                                            const float* __restrict__ fc2_b,
                                            char* __restrict__ ws,
                                            float* __restrict__ out)
{
  const int b = blockIdx.x, lane = threadIdx.x;
  const float* hl = (const float*)(ws + OFF_HLAST);
  float acc[10];
  #pragma unroll
  for (int c = 0; c < 10; ++c) acc[c] = 0.0f;
  #pragma unroll 1
  for (int kk = 0; kk < 16; ++kk) {
    const int k = lane * 16 + kk;
    const float hv = (k < 512) ? hl[(size_t)b * 512 + k]
                               : hl[((size_t)(64 + b)) * 512 + (k - 512)];
    #pragma unroll
    for (int c = 0; c < 10; ++c) acc[c] += hv * fc2_w[c * 1024 + k];
  }
  #pragma unroll
  for (int c = 0; c < 10; ++c) {
    #pragma unroll
    for (int off = 32; off >= 1; off >>= 1)
      acc[c] += __shfl_down(acc[c], off);
  }
  if (lane == 0) {
    float lg[10];
    float mx = -3.0e38f;
    #pragma unroll
    for (int c = 0; c < 10; ++c) { lg[c] = acc[c] + fc2_b[c]; mx = fmaxf(mx, lg[c]); }
    float s = 0.0f;
    #pragma unroll
    for (int c = 0; c < 10; ++c) { lg[c] = expf(lg[c] - mx); s += lg[c]; }
    const float inv = 1.0f / s;
    #pragma unroll
    for (int c = 0; c < 10; ++c) out[32832 + b * 10 + c] = lg[c] * inv;
  }
}

extern "C" void kernel_launch(void* const* d_in, const int* in_sizes, int n_in,
                              void* d_out, int out_size, void* d_ws, size_t ws_size,
                              hipStream_t stream)
{
  (void)in_sizes; (void)n_in; (void)out_size; (void)ws_size;
  const int*   x      = (const int*)d_in[0];
  const float* emb    = (const float*)d_in[1];
  const float* wih_f  = (const float*)d_in[2];
  const float* whh_f  = (const float*)d_in[3];
  const float* b_f    = (const float*)d_in[4];
  const float* wih_b  = (const float*)d_in[5];
  const float* whh_b  = (const float*)d_in[6];
  const float* b_b    = (const float*)d_in[7];
  const float* fc_w   = (const float*)d_in[8];
  const float* fc_b   = (const float*)d_in[9];
  const float* fc2_w  = (const float*)d_in[10];
  const float* fc2_b  = (const float*)d_in[11];
  const float* trans  = (const float*)d_in[12];
  char* ws = (char*)d_ws;
  float* out = (float*)d_out;

  prep_k<<<dim3(8513), dim3(256), 0, stream>>>(x, emb, ws);
  lstm_k<<<dim3(256), dim3(256), 0, stream>>>(wih_f, whh_f, b_f, wih_b, whh_b, b_b, ws);
  emis_k<<<dim3(128), dim3(256), 0, stream>>>(fc_w, fc_b, ws);
  cls_k<<<dim3(64), dim3(64), 0, stream>>>(fc2_w, fc2_b, ws, out);
  viterbi_k<<<dim3(64), dim3(64), 0, stream>>>(trans, ws, out);
}